// Round 1
// baseline (531.903 us; speedup 1.0000x reference)
//
#include <hip/hip_runtime.h>
#include <hip/hip_bf16.h>

typedef __attribute__((ext_vector_type(8))) short short8;
typedef __attribute__((ext_vector_type(4))) float f32x4;
typedef __attribute__((ext_vector_type(4))) float f4;

#define MFMA(a, b, c) __builtin_amdgcn_mfma_f32_16x16x32_bf16(a, b, c, 0, 0, 0)

constexpr int Bc = 4, L = 2048, H = 16, E = 64;
constexpr int QBLK = 64, KVBLK = 64;
constexpr int LDV = 72, LDP = 72;  // LDS row strides (elements); multiples of 8 keep 16B align

__device__ __forceinline__ short f2bf(float f) {
  union { float f; unsigned u; } x;
  x.f = f;
  unsigned r = x.u + 0x7fffu + ((x.u >> 16) & 1u);  // RNE
  return (short)(r >> 16);
}

__device__ __forceinline__ short8 pack8(f4 a, f4 b, float sc) {
  short8 r;
  r[0] = f2bf(a[0] * sc); r[1] = f2bf(a[1] * sc);
  r[2] = f2bf(a[2] * sc); r[3] = f2bf(a[3] * sc);
  r[4] = f2bf(b[0] * sc); r[5] = f2bf(b[1] * sc);
  r[6] = f2bf(b[2] * sc); r[7] = f2bf(b[3] * sc);
  return r;
}

__global__ __launch_bounds__(256, 2)
void fattn_kernel(const float* __restrict__ Q, const float* __restrict__ K,
                  const float* __restrict__ V, float* __restrict__ O) {
  const int qtile = blockIdx.x;
  const int bh = blockIdx.y;
  const int b = bh / H, h = bh % H;
  const int tid = threadIdx.x;
  const int wid = tid >> 6;
  const int lane = tid & 63;
  const int lg = lane >> 4;   // lane group 0..3
  const int lm = lane & 15;   // lane within group

  __shared__ __align__(16) short Vs[E * LDV];        // V^T: [e][key]
  __shared__ __align__(16) short Ps[4][16 * LDP];    // per-wave P: [qrow][key]

  const int qbase = qtile * QBLK;
  const int qrow0 = qbase + wid * 16;

  // ---- Q fragments (A operand), pre-scaled by 1/sqrt(E)=0.125 ----
  short8 qf[2];
  {
    const float* qp = Q + (((size_t)b * L + (qrow0 + lm)) * H + h) * E + lg * 8;
#pragma unroll
    for (int kc = 0; kc < 2; ++kc) {
      f4 a = *(const f4*)(qp + kc * 32);
      f4 c = *(const f4*)(qp + kc * 32 + 4);
      qf[kc] = pack8(a, c, 0.125f);
    }
  }

  f32x4 o[4];
#pragma unroll
  for (int et = 0; et < 4; ++et) o[et] = (f32x4){0.f, 0.f, 0.f, 0.f};
  float mrow[4], lrow[4];
#pragma unroll
  for (int r = 0; r < 4; ++r) { mrow[r] = -1e30f; lrow[r] = 0.f; }

  const float* kbase = K + (((size_t)b * L) * H + h) * E;
  const float* vbase = V + (((size_t)b * L) * H + h) * E;

  const int nkv = qtile + 1;
  for (int kt = 0; kt < nkv; ++kt) {
    __syncthreads();  // prior-iter PV reads of Vs done before overwrite

    // ---- stage V^T into LDS (coalesced global read, transposed write) ----
    {
      const int key = tid >> 2;          // 0..63
      const int eb = (tid & 3) * 16;     // 0,16,32,48
      const float* vp = vbase + (size_t)(kt * KVBLK + key) * (H * E) + eb;
#pragma unroll
      for (int i = 0; i < 4; ++i) {
        f4 v = *(const f4*)(vp + i * 4);
        Vs[(eb + i * 4 + 0) * LDV + key] = f2bf(v[0]);
        Vs[(eb + i * 4 + 1) * LDV + key] = f2bf(v[1]);
        Vs[(eb + i * 4 + 2) * LDV + key] = f2bf(v[2]);
        Vs[(eb + i * 4 + 3) * LDV + key] = f2bf(v[3]);
      }
    }

    // ---- S = (Q*scale) K^T : 4 col-tiles of 16 keys, K loaded from global ----
    f32x4 s[4];
#pragma unroll
    for (int ct = 0; ct < 4; ++ct) {
      f32x4 acc = (f32x4){0.f, 0.f, 0.f, 0.f};
      const float* kp = kbase + (size_t)(kt * KVBLK + ct * 16 + lm) * (H * E) + lg * 8;
#pragma unroll
      for (int kc = 0; kc < 2; ++kc) {
        f4 a = *(const f4*)(kp + kc * 32);
        f4 c = *(const f4*)(kp + kc * 32 + 4);
        short8 kf = pack8(a, c, 1.0f);
        acc = MFMA(qf[kc], kf, acc);
      }
      s[ct] = acc;
    }

    // ---- causal mask (only the diagonal tile) ----
    if (kt == nkv - 1) {
#pragma unroll
      for (int ct = 0; ct < 4; ++ct) {
        const int sg = kt * KVBLK + ct * 16 + lm;
#pragma unroll
        for (int r = 0; r < 4; ++r) {
          const int qg = qrow0 + lg * 4 + r;
          if (sg > qg) s[ct][r] = -1e30f;
        }
      }
    }

    // ---- online softmax (row = lg*4+r, reduce over 16 lanes lm) ----
#pragma unroll
    for (int r = 0; r < 4; ++r) {
      float tm = fmaxf(fmaxf(s[0][r], s[1][r]), fmaxf(s[2][r], s[3][r]));
      tm = fmaxf(tm, __shfl_xor(tm, 1));
      tm = fmaxf(tm, __shfl_xor(tm, 2));
      tm = fmaxf(tm, __shfl_xor(tm, 4));
      tm = fmaxf(tm, __shfl_xor(tm, 8));
      const float mnew = fmaxf(mrow[r], tm);
      const float sc = __expf(mrow[r] - mnew);
      mrow[r] = mnew;
      float rs = 0.f;
#pragma unroll
      for (int ct = 0; ct < 4; ++ct) {
        const float p = __expf(s[ct][r] - mnew);
        s[ct][r] = p;
        rs += p;
      }
      rs += __shfl_xor(rs, 1);
      rs += __shfl_xor(rs, 2);
      rs += __shfl_xor(rs, 4);
      rs += __shfl_xor(rs, 8);
      lrow[r] = lrow[r] * sc + rs;
#pragma unroll
      for (int et = 0; et < 4; ++et) o[et][r] *= sc;
    }

    // ---- P (bf16) to per-wave LDS for A-fragment re-layout ----
#pragma unroll
    for (int ct = 0; ct < 4; ++ct)
#pragma unroll
      for (int r = 0; r < 4; ++r)
        Ps[wid][(lg * 4 + r) * LDP + ct * 16 + lm] = f2bf(s[ct][r]);

    __syncthreads();  // Vs staged + Ps visible

    // ---- O += P V ----
    short8 pf[2];
    pf[0] = *(const short8*)&Ps[wid][lm * LDP + 0 * 32 + lg * 8];
    pf[1] = *(const short8*)&Ps[wid][lm * LDP + 1 * 32 + lg * 8];
#pragma unroll
    for (int et = 0; et < 4; ++et) {
#pragma unroll
      for (int kc = 0; kc < 2; ++kc) {
        short8 vf = *(const short8*)&Vs[(et * 16 + lm) * LDV + kc * 32 + lg * 8];
        o[et] = MFMA(pf[kc], vf, o[et]);
      }
    }
  }

  // ---- epilogue: normalize + store fp32 ----
  float* op = O + (((size_t)b * L + qrow0) * H + h) * E;
#pragma unroll
  for (int r = 0; r < 4; ++r) {
    const float inv = 1.f / lrow[r];
    const int row = lg * 4 + r;
#pragma unroll
    for (int et = 0; et < 4; ++et)
      op[(size_t)row * (H * E) + et * 16 + lm] = o[et][r] * inv;
  }
}

extern "C" void kernel_launch(void* const* d_in, const int* in_sizes, int n_in,
                              void* d_out, int out_size, void* d_ws, size_t ws_size,
                              hipStream_t stream) {
  const float* Q = (const float*)d_in[0];
  const float* K = (const float*)d_in[1];
  const float* V = (const float*)d_in[2];
  float* Out = (float*)d_out;
  dim3 grid(L / QBLK, Bc * H);
  fattn_kernel<<<grid, 256, 0, stream>>>(Q, K, V, Out);
}

// Round 3
// 472.497 us; speedup vs baseline: 1.1257x; 1.1257x over previous
//
#include <hip/hip_runtime.h>
#include <hip/hip_bf16.h>

typedef __attribute__((ext_vector_type(8))) short short8;
typedef __attribute__((ext_vector_type(4))) float f32x4;
typedef __attribute__((ext_vector_type(4))) float f4;
typedef __attribute__((ext_vector_type(2))) unsigned uint2v;

#define MFMA(a, b, c) __builtin_amdgcn_mfma_f32_16x16x32_bf16(a, b, c, 0, 0, 0)

constexpr int B_ = 4, L = 2048, H = 16, E = 64;
constexpr int QBLK = 64, KVBLK = 64;
constexpr int LDP = 72;                    // Pt row stride in shorts: 64 keys + 8 pad
constexpr size_t NELEM = (size_t)B_ * L * H * E;        // 8388608
constexpr size_t WS_NEEDED = NELEM * 2 * 3;             // 50,331,648 B

__device__ __forceinline__ unsigned short f2bf(float f) {
  union { float f; unsigned u; } x;
  x.f = f;
  unsigned r = x.u + 0x7fffu + ((x.u >> 16) & 1u);  // RNE
  return (unsigned short)(r >> 16);
}
__device__ __forceinline__ unsigned pack2(float a, float b) {
  return (unsigned)f2bf(a) | ((unsigned)f2bf(b) << 16);
}

// ================= prepass 1: Q (scaled) and K -> head-major bf16 [b][h][l][e]
__global__ __launch_bounds__(256)
void convert_qk(const float* __restrict__ Q, const float* __restrict__ K,
                unsigned short* __restrict__ Qb, unsigned short* __restrict__ Kb) {
  const bool isq = (blockIdx.y == 0);
  const float* in = isq ? Q : K;
  unsigned short* out = isq ? Qb : Kb;
  const float scale = isq ? 0.125f : 1.0f;
  const size_t t = (size_t)blockIdx.x * 256 + threadIdx.x;   // 8 elems/thread
  const size_t row = t >> 3;                                  // (b*L+l)*H+h
  const int e0 = ((int)t & 7) * 8;
  const int h = (int)(row % H);
  const size_t bl = row / H;
  const int l = (int)(bl % L);
  const int b = (int)(bl / L);
  f4 a = *(const f4*)(in + t * 8);
  f4 c = *(const f4*)(in + t * 8 + 4);
  short8 o;
  o[0] = (short)f2bf(a[0] * scale); o[1] = (short)f2bf(a[1] * scale);
  o[2] = (short)f2bf(a[2] * scale); o[3] = (short)f2bf(a[3] * scale);
  o[4] = (short)f2bf(c[0] * scale); o[5] = (short)f2bf(c[1] * scale);
  o[6] = (short)f2bf(c[2] * scale); o[7] = (short)f2bf(c[3] * scale);
  *(short8*)(out + (((size_t)b * H + h) * L + l) * E + e0) = o;
}

// ================= prepass 2: V -> transposed bf16 [b][h][e][l]
__global__ __launch_bounds__(256)
void transpose_v(const float* __restrict__ V, unsigned short* __restrict__ Vt) {
  const int blk = blockIdx.x;
  const int st = blk % (L / KVBLK);
  const int bh = blk / (L / KVBLK);
  const int h = bh % H, b = bh / H;
  __shared__ unsigned short Ts[E][KVBLK + 8];
  const int tid = threadIdx.x;
  const int r = tid >> 3, e0 = (tid & 7) * 8;
  const float* vp = V + (((size_t)b * L + st * KVBLK) * H + h) * E;
#pragma unroll
  for (int rr = 0; rr < 2; ++rr) {
    const int row = rr * 32 + r;
    f4 a = *(const f4*)(vp + (size_t)row * (H * E) + e0);
    f4 c = *(const f4*)(vp + (size_t)row * (H * E) + e0 + 4);
#pragma unroll
    for (int j = 0; j < 4; ++j) Ts[e0 + j][row] = f2bf(a[j]);
#pragma unroll
    for (int j = 0; j < 4; ++j) Ts[e0 + 4 + j][row] = f2bf(c[j]);
  }
  __syncthreads();
  const int e = tid >> 2, k0 = (tid & 3) * 16;
  unsigned short* op = Vt + (((size_t)b * H + h) * E + e) * L + st * KVBLK + k0;
  *(short8*)op = *(const short8*)&Ts[e][k0];
  *(short8*)(op + 8) = *(const short8*)&Ts[e][k0 + 8];
}

// ================= main: barrier-free flash attention, swapped QK^T
__global__ __launch_bounds__(256, 4)
void fattn2(const unsigned short* __restrict__ Qb, const unsigned short* __restrict__ Kb,
            const unsigned short* __restrict__ Vt, float* __restrict__ O) {
  const int qtile = (int)(gridDim.x - 1) - blockIdx.x;  // longest blocks first
  const int bh = blockIdx.y;
  const int b = bh / H, h = bh % H;
  const int tid = threadIdx.x;
  const int wid = tid >> 6;
  const int lane = tid & 63;
  const int lg = lane >> 4, lm = lane & 15;
  const int qrow0 = qtile * QBLK + wid * 16;

  __shared__ __align__(16) unsigned short Pt[4][16 * LDP];  // per-wave, no barriers

  // Q fragment (B operand of swapped QK^T): Q[q=lm][e = kc*32 + lg*8 + j]
  const unsigned short* qbase = Qb + ((size_t)bh * L + qrow0 + lm) * E + lg * 8;
  short8 qf0 = *(const short8*)qbase;
  short8 qf1 = *(const short8*)(qbase + 32);

  f32x4 o[4];
#pragma unroll
  for (int et = 0; et < 4; ++et) o[et] = (f32x4){0.f, 0.f, 0.f, 0.f};
  float m = -1e30f, lsum = 0.f;

  const unsigned short* kbase = Kb + (size_t)bh * L * E;
  const unsigned short* vbase = Vt + (size_t)bh * E * L;

  const int nkv = qtile + 1;
  for (int kt = 0; kt < nkv; ++kt) {
    const bool diag = (kt == nkv - 1);

    // ---- S^T tiles: stl[ct][r] = S^T[key = kt*64 + ct*16 + lg*4 + r][q = qrow0 + lm]
    f32x4 stl[4];
#pragma unroll
    for (int ct = 0; ct < 4; ++ct) {
      if (diag && ct > wid) {  // fully-masked tile on the diagonal: skip
        stl[ct] = (f32x4){-1e30f, -1e30f, -1e30f, -1e30f};
        continue;
      }
      const unsigned short* kp = kbase + (size_t)(kt * KVBLK + ct * 16 + lm) * E + lg * 8;
      short8 k0 = *(const short8*)kp;
      short8 k1 = *(const short8*)(kp + 32);
      f32x4 acc = (f32x4){0.f, 0.f, 0.f, 0.f};
      acc = MFMA(k0, qf0, acc);
      acc = MFMA(k1, qf1, acc);
      stl[ct] = acc;
    }

    // ---- causal mask: only tile ct == wid is partial on the diagonal
    if (diag) {
#pragma unroll
      for (int ct = 0; ct < 4; ++ct) {
        if (ct == wid) {
#pragma unroll
          for (int r = 0; r < 4; ++r) {
            const int key = kt * KVBLK + ct * 16 + lg * 4 + r;
            if (key > qrow0 + lm) stl[ct][r] = -1e30f;
          }
        }
      }
    }

    // ---- online softmax (stats per q = lm; reduce over lane groups)
    float tm = stl[0][0];
#pragma unroll
    for (int ct = 0; ct < 4; ++ct)
#pragma unroll
      for (int r = 0; r < 4; ++r) tm = fmaxf(tm, stl[ct][r]);
    tm = fmaxf(tm, __shfl_xor(tm, 16));
    tm = fmaxf(tm, __shfl_xor(tm, 32));
    const float mnew = fmaxf(m, tm);
    const float sc = __expf(m - mnew);
    m = mnew;
    float rs = 0.f;
#pragma unroll
    for (int ct = 0; ct < 4; ++ct)
#pragma unroll
      for (int r = 0; r < 4; ++r) {
        const float p = __expf(stl[ct][r] - mnew);
        stl[ct][r] = p;
        rs += p;
      }
    rs += __shfl_xor(rs, 16);
    rs += __shfl_xor(rs, 32);
    lsum = lsum * sc + rs;

    // ---- rescale O by per-row sc (row q = lg*4 + r; sc lives at lane lm = lg*4+r)
    float scr[4];
#pragma unroll
    for (int r = 0; r < 4; ++r) scr[r] = __shfl(sc, lg * 20 + r);
#pragma unroll
    for (int et = 0; et < 4; ++et)
#pragma unroll
      for (int r = 0; r < 4; ++r) o[et][r] *= scr[r];

    // ---- P^T -> A-fragment re-layout via per-wave LDS (no barrier needed)
#pragma unroll
    for (int ct = 0; ct < 4; ++ct) {
      uint2v w;
      w[0] = pack2(stl[ct][0], stl[ct][1]);
      w[1] = pack2(stl[ct][2], stl[ct][3]);
      *(uint2v*)&Pt[wid][lm * LDP + ct * 16 + lg * 4] = w;  // Pt[q][key], 8B store
    }
    short8 pf0 = *(const short8*)&Pt[wid][lm * LDP + 0 * 32 + lg * 8];
    short8 pf1 = *(const short8*)&Pt[wid][lm * LDP + 1 * 32 + lg * 8];

    // ---- O += P V  (V^T fragments straight from global bf16)
#pragma unroll
    for (int et = 0; et < 4; ++et) {
      const unsigned short* vp = vbase + (size_t)(et * 16 + lm) * L + kt * KVBLK + lg * 8;
      short8 v0 = *(const short8*)vp;
      short8 v1 = *(const short8*)(vp + 32);
      o[et] = MFMA(pf0, v0, o[et]);
      o[et] = MFMA(pf1, v1, o[et]);
    }
  }

  // ---- epilogue: normalize + store fp32 (row q = qrow0 + lg*4 + r, col e = et*16+lm)
  float linv[4];
#pragma unroll
  for (int r = 0; r < 4; ++r) linv[r] = 1.f / __shfl(lsum, lg * 20 + r);
  float* op = O + (((size_t)b * L + qrow0 + lg * 4) * H + h) * E;
#pragma unroll
  for (int r = 0; r < 4; ++r)
#pragma unroll
    for (int et = 0; et < 4; ++et)
      op[(size_t)r * (H * E) + et * 16 + lm] = o[et][r] * linv[r];
}

// ================= fallback (verified v1) for tiny workspaces ==============
constexpr int LDV_F = 72, LDP_F = 72;
__global__ __launch_bounds__(256, 2)
void fattn_v1(const float* __restrict__ Q, const float* __restrict__ K,
              const float* __restrict__ V, float* __restrict__ O) {
  const int qtile = blockIdx.x;
  const int bh = blockIdx.y;
  const int b = bh / H, h = bh % H;
  const int tid = threadIdx.x;
  const int wid = tid >> 6;
  const int lane = tid & 63;
  const int lg = lane >> 4, lm = lane & 15;
  __shared__ __align__(16) short Vs[E * LDV_F];
  __shared__ __align__(16) short Ps[4][16 * LDP_F];
  const int qrow0 = qtile * QBLK + wid * 16;
  short8 qf[2];
  {
    const float* qp = Q + (((size_t)b * L + (qrow0 + lm)) * H + h) * E + lg * 8;
#pragma unroll
    for (int kc = 0; kc < 2; ++kc) {
      f4 a = *(const f4*)(qp + kc * 32);
      f4 c = *(const f4*)(qp + kc * 32 + 4);
      short8 r;
      r[0] = (short)f2bf(a[0] * 0.125f); r[1] = (short)f2bf(a[1] * 0.125f);
      r[2] = (short)f2bf(a[2] * 0.125f); r[3] = (short)f2bf(a[3] * 0.125f);
      r[4] = (short)f2bf(c[0] * 0.125f); r[5] = (short)f2bf(c[1] * 0.125f);
      r[6] = (short)f2bf(c[2] * 0.125f); r[7] = (short)f2bf(c[3] * 0.125f);
      qf[kc] = r;
    }
  }
  f32x4 o[4];
#pragma unroll
  for (int et = 0; et < 4; ++et) o[et] = (f32x4){0.f, 0.f, 0.f, 0.f};
  float mrow[4], lrow[4];
#pragma unroll
  for (int r = 0; r < 4; ++r) { mrow[r] = -1e30f; lrow[r] = 0.f; }
  const float* kbase = K + (((size_t)b * L) * H + h) * E;
  const float* vbase = V + (((size_t)b * L) * H + h) * E;
  const int nkv = qtile + 1;
  for (int kt = 0; kt < nkv; ++kt) {
    __syncthreads();
    {
      const int key = tid >> 2;
      const int eb = (tid & 3) * 16;
      const float* vp = vbase + (size_t)(kt * KVBLK + key) * (H * E) + eb;
#pragma unroll
      for (int i = 0; i < 4; ++i) {
        f4 v = *(const f4*)(vp + i * 4);
        Vs[(eb + i * 4 + 0) * LDV_F + key] = (short)f2bf(v[0]);
        Vs[(eb + i * 4 + 1) * LDV_F + key] = (short)f2bf(v[1]);
        Vs[(eb + i * 4 + 2) * LDV_F + key] = (short)f2bf(v[2]);
        Vs[(eb + i * 4 + 3) * LDV_F + key] = (short)f2bf(v[3]);
      }
    }
    f32x4 s[4];
#pragma unroll
    for (int ct = 0; ct < 4; ++ct) {
      f32x4 acc = (f32x4){0.f, 0.f, 0.f, 0.f};
      const float* kp = kbase + (size_t)(kt * KVBLK + ct * 16 + lm) * (H * E) + lg * 8;
#pragma unroll
      for (int kc = 0; kc < 2; ++kc) {
        f4 a = *(const f4*)(kp + kc * 32);
        f4 c = *(const f4*)(kp + kc * 32 + 4);
        short8 kf;
        kf[0] = (short)f2bf(a[0]); kf[1] = (short)f2bf(a[1]);
        kf[2] = (short)f2bf(a[2]); kf[3] = (short)f2bf(a[3]);
        kf[4] = (short)f2bf(c[0]); kf[5] = (short)f2bf(c[1]);
        kf[6] = (short)f2bf(c[2]); kf[7] = (short)f2bf(c[3]);
        acc = MFMA(qf[kc], kf, acc);
      }
      s[ct] = acc;
    }
    if (kt == nkv - 1) {
#pragma unroll
      for (int ct = 0; ct < 4; ++ct) {
        const int sg = kt * KVBLK + ct * 16 + lm;
#pragma unroll
        for (int r = 0; r < 4; ++r)
          if (sg > qrow0 + lg * 4 + r) s[ct][r] = -1e30f;
      }
    }
#pragma unroll
    for (int r = 0; r < 4; ++r) {
      float tm = fmaxf(fmaxf(s[0][r], s[1][r]), fmaxf(s[2][r], s[3][r]));
      tm = fmaxf(tm, __shfl_xor(tm, 1));
      tm = fmaxf(tm, __shfl_xor(tm, 2));
      tm = fmaxf(tm, __shfl_xor(tm, 4));
      tm = fmaxf(tm, __shfl_xor(tm, 8));
      const float mnew = fmaxf(mrow[r], tm);
      const float sc = __expf(mrow[r] - mnew);
      mrow[r] = mnew;
      float rs = 0.f;
#pragma unroll
      for (int ct = 0; ct < 4; ++ct) {
        const float p = __expf(s[ct][r] - mnew);
        s[ct][r] = p;
        rs += p;
      }
      rs += __shfl_xor(rs, 1);
      rs += __shfl_xor(rs, 2);
      rs += __shfl_xor(rs, 4);
      rs += __shfl_xor(rs, 8);
      lrow[r] = lrow[r] * sc + rs;
#pragma unroll
      for (int et = 0; et < 4; ++et) o[et][r] *= sc;
    }
#pragma unroll
    for (int ct = 0; ct < 4; ++ct)
#pragma unroll
      for (int r = 0; r < 4; ++r)
        Ps[wid][(lg * 4 + r) * LDP_F + ct * 16 + lm] = (short)f2bf(s[ct][r]);
    __syncthreads();
    short8 pf[2];
    pf[0] = *(const short8*)&Ps[wid][lm * LDP_F + 0 * 32 + lg * 8];
    pf[1] = *(const short8*)&Ps[wid][lm * LDP_F + 1 * 32 + lg * 8];
#pragma unroll
    for (int et = 0; et < 4; ++et)
#pragma unroll
      for (int kc = 0; kc < 2; ++kc) {
        short8 vf = *(const short8*)&Vs[(et * 16 + lm) * LDV_F + kc * 32 + lg * 8];
        o[et] = MFMA(pf[kc], vf, o[et]);
      }
  }
  float* op = O + (((size_t)b * L + qrow0) * H + h) * E;
#pragma unroll
  for (int r = 0; r < 4; ++r) {
    const float inv = 1.f / lrow[r];
#pragma unroll
    for (int et = 0; et < 4; ++et)
      op[(size_t)(lg * 4 + r) * (H * E) + et * 16 + lm] = o[et][r] * inv;
  }
}

extern "C" void kernel_launch(void* const* d_in, const int* in_sizes, int n_in,
                              void* d_out, int out_size, void* d_ws, size_t ws_size,
                              hipStream_t stream) {
  const float* Q = (const float*)d_in[0];
  const float* K = (const float*)d_in[1];
  const float* V = (const float*)d_in[2];
  float* Out = (float*)d_out;
  if (ws_size >= WS_NEEDED) {
    unsigned short* Qb = (unsigned short*)d_ws;
    unsigned short* Kb = Qb + NELEM;
    unsigned short* Vt = Kb + NELEM;
    dim3 gc((unsigned)(NELEM / (256 * 8)), 2);
    convert_qk<<<gc, 256, 0, stream>>>(Q, K, Qb, Kb);
    transpose_v<<<B_ * H * (L / KVBLK), 256, 0, stream>>>(V, Vt);
    dim3 grid(L / QBLK, B_ * H);
    fattn2<<<grid, 256, 0, stream>>>(Qb, Kb, Vt, Out);
  } else {
    dim3 grid(L / QBLK, B_ * H);
    fattn_v1<<<grid, 256, 0, stream>>>(Q, K, V, Out);
  }
}

// Round 4
// 283.072 us; speedup vs baseline: 1.8790x; 1.6692x over previous
//
#include <hip/hip_runtime.h>
#include <hip/hip_bf16.h>

typedef __attribute__((ext_vector_type(8))) short short8;
typedef __attribute__((ext_vector_type(4))) float f32x4;
typedef __attribute__((ext_vector_type(4))) float f4;
typedef __attribute__((ext_vector_type(2))) unsigned uint2v;

#define MFMA(a, b, c) __builtin_amdgcn_mfma_f32_16x16x32_bf16(a, b, c, 0, 0, 0)

constexpr int B_ = 4, L = 2048, H = 16, E = 64;
constexpr int QBLK = 64, KVBLK = 64;
constexpr int LDP = 72;                    // Pt row stride in shorts: 64 keys + 8 pad
constexpr size_t NELEM = (size_t)B_ * L * H * E;        // 8388608
constexpr size_t WS_NEEDED = NELEM * 2 * 3;             // 50,331,648 B

__device__ __forceinline__ unsigned short f2bf(float f) {
  union { float f; unsigned u; } x;
  x.f = f;
  unsigned r = x.u + 0x7fffu + ((x.u >> 16) & 1u);  // RNE
  return (unsigned short)(r >> 16);
}
__device__ __forceinline__ unsigned pack2(float a, float b) {
  return (unsigned)f2bf(a) | ((unsigned)f2bf(b) << 16);
}

// ================= prepass 1: Q (scaled) and K -> head-major bf16 [b][h][l][e]
__global__ __launch_bounds__(256)
void convert_qk(const float* __restrict__ Q, const float* __restrict__ K,
                unsigned short* __restrict__ Qb, unsigned short* __restrict__ Kb) {
  const bool isq = (blockIdx.y == 0);
  const float* in = isq ? Q : K;
  unsigned short* out = isq ? Qb : Kb;
  const float scale = isq ? 0.125f : 1.0f;
  const size_t t = (size_t)blockIdx.x * 256 + threadIdx.x;   // 8 elems/thread
  const size_t row = t >> 3;                                  // (b*L+l)*H+h
  const int e0 = ((int)t & 7) * 8;
  const int h = (int)(row % H);
  const size_t bl = row / H;
  const int l = (int)(bl % L);
  const int b = (int)(bl / L);
  f4 a = *(const f4*)(in + t * 8);
  f4 c = *(const f4*)(in + t * 8 + 4);
  short8 o;
  o[0] = (short)f2bf(a[0] * scale); o[1] = (short)f2bf(a[1] * scale);
  o[2] = (short)f2bf(a[2] * scale); o[3] = (short)f2bf(a[3] * scale);
  o[4] = (short)f2bf(c[0] * scale); o[5] = (short)f2bf(c[1] * scale);
  o[6] = (short)f2bf(c[2] * scale); o[7] = (short)f2bf(c[3] * scale);
  *(short8*)(out + (((size_t)b * H + h) * L + l) * E + e0) = o;
}

// ================= prepass 2: V -> tiled-transposed bf16 [bh][kt][e][64]
__global__ __launch_bounds__(256)
void transpose_v(const float* __restrict__ V, unsigned short* __restrict__ Vt) {
  const int blk = blockIdx.x;
  const int st = blk % (L / KVBLK);
  const int bh = blk / (L / KVBLK);
  const int h = bh % H, b = bh / H;
  __shared__ unsigned short Ts[E][KVBLK + 8];
  const int tid = threadIdx.x;
  const int r = tid >> 3, e0 = (tid & 7) * 8;
  const float* vp = V + (((size_t)b * L + st * KVBLK) * H + h) * E;
#pragma unroll
  for (int rr = 0; rr < 2; ++rr) {
    const int row = rr * 32 + r;
    f4 a = *(const f4*)(vp + (size_t)row * (H * E) + e0);
    f4 c = *(const f4*)(vp + (size_t)row * (H * E) + e0 + 4);
#pragma unroll
    for (int j = 0; j < 4; ++j) Ts[e0 + j][row] = f2bf(a[j]);
#pragma unroll
    for (int j = 0; j < 4; ++j) Ts[e0 + 4 + j][row] = f2bf(c[j]);
  }
  __syncthreads();
  // tiled output: Vt[bh][st][e][k_local], tile = 64x64 contiguous (8 KB)
  const int e = tid >> 2, k0 = (tid & 3) * 16;
  unsigned short* op = Vt + ((size_t)bh * (L / KVBLK) + st) * (E * KVBLK) + e * KVBLK + k0;
  *(short8*)op = *(const short8*)&Ts[e][k0];
  *(short8*)(op + 8) = *(const short8*)&Ts[e][k0 + 8];
}

// ================= main: barrier-free flash attention, swapped QK^T
__global__ __launch_bounds__(256, 4)
void fattn2(const unsigned short* __restrict__ Qb, const unsigned short* __restrict__ Kb,
            const unsigned short* __restrict__ Vt, float* __restrict__ O) {
  // grid: x = bh (64), y = qtile (32). Blocks sharing a CU (stride-256 in flat
  // index) get the same bh and qtiles {q0, q0+4, ...}: balanced work + L2 reuse.
  const int bh = blockIdx.x;
  const int qtile = blockIdx.y;
  const int b = bh >> 4, h = bh & 15;
  const int tid = threadIdx.x;
  const int wid = tid >> 6;
  const int lane = tid & 63;
  const int lg = lane >> 4, lm = lane & 15;
  const int qrow0 = qtile * QBLK + wid * 16;

  __shared__ __align__(16) unsigned short Pt[4][16 * LDP];  // per-wave, no barriers

  // Q fragment (B operand of swapped QK^T): Q[q=lm][e = kc*32 + lg*8 + j]
  const unsigned short* qbase = Qb + ((size_t)bh * L + qrow0 + lm) * E + lg * 8;
  short8 qf0 = *(const short8*)qbase;
  short8 qf1 = *(const short8*)(qbase + 32);

  f32x4 o[4];
#pragma unroll
  for (int et = 0; et < 4; ++et) o[et] = (f32x4){0.f, 0.f, 0.f, 0.f};
  float m = -1e30f, lsum = 0.f;

  const unsigned short* kbase = Kb + (size_t)bh * L * E;
  const unsigned short* vbase = Vt + (size_t)bh * L * E;  // tiled: [kt][e][64]

  const int nkv = qtile + 1;
  for (int kt = 0; kt < nkv; ++kt) {
    const bool diag = (kt == nkv - 1);

    // ---- S^T tiles: stl[ct][r] = S^T[key = kt*64 + ct*16 + lg*4 + r][q = qrow0 + lm]
    f32x4 stl[4];
#pragma unroll
    for (int ct = 0; ct < 4; ++ct) {
      if (diag && ct > wid) {  // fully-masked tile on the diagonal: skip
        stl[ct] = (f32x4){-1e30f, -1e30f, -1e30f, -1e30f};
        continue;
      }
      const unsigned short* kp = kbase + (size_t)(kt * KVBLK + ct * 16 + lm) * E + lg * 8;
      short8 k0 = *(const short8*)kp;
      short8 k1 = *(const short8*)(kp + 32);
      f32x4 acc = (f32x4){0.f, 0.f, 0.f, 0.f};
      acc = MFMA(k0, qf0, acc);
      acc = MFMA(k1, qf1, acc);
      stl[ct] = acc;
    }

    // ---- V fragments: issue loads NOW so L2 latency hides under softmax ----
    // V^T tile row e = et*16+lm, key offset kc*32 + lg*8 (tile stride 64 shorts)
    short8 vf[8];
    {
      const unsigned short* vp = vbase + (size_t)kt * (E * KVBLK) + (size_t)lm * KVBLK + lg * 8;
#pragma unroll
      for (int et = 0; et < 4; ++et) {
        vf[et * 2 + 0] = *(const short8*)(vp + et * 16 * KVBLK);
        vf[et * 2 + 1] = *(const short8*)(vp + et * 16 * KVBLK + 32);
      }
    }

    // ---- causal mask: only tile ct == wid is partial on the diagonal
    if (diag) {
#pragma unroll
      for (int ct = 0; ct < 4; ++ct) {
        if (ct == wid) {
#pragma unroll
          for (int r = 0; r < 4; ++r) {
            const int key = kt * KVBLK + ct * 16 + lg * 4 + r;
            if (key > qrow0 + lm) stl[ct][r] = -1e30f;
          }
        }
      }
    }

    // ---- online softmax (stats per q = lm; reduce over lane groups)
    float tm = stl[0][0];
#pragma unroll
    for (int ct = 0; ct < 4; ++ct)
#pragma unroll
      for (int r = 0; r < 4; ++r) tm = fmaxf(tm, stl[ct][r]);
    tm = fmaxf(tm, __shfl_xor(tm, 16));
    tm = fmaxf(tm, __shfl_xor(tm, 32));
    const float mnew = fmaxf(m, tm);
    const float sc = __expf(m - mnew);
    m = mnew;
    float rs = 0.f;
#pragma unroll
    for (int ct = 0; ct < 4; ++ct)
#pragma unroll
      for (int r = 0; r < 4; ++r) {
        const float p = __expf(stl[ct][r] - mnew);
        stl[ct][r] = p;
        rs += p;
      }
    rs += __shfl_xor(rs, 16);
    rs += __shfl_xor(rs, 32);
    lsum = lsum * sc + rs;

    // ---- rescale O by per-row sc (row q = lg*4 + r; sc lives at lane with lm = lg*4+r)
    float scr[4];
#pragma unroll
    for (int r = 0; r < 4; ++r) scr[r] = __shfl(sc, lg * 20 + r);
#pragma unroll
    for (int et = 0; et < 4; ++et)
#pragma unroll
      for (int r = 0; r < 4; ++r) o[et][r] *= scr[r];

    // ---- P^T -> A-fragment re-layout via per-wave LDS (no barrier needed)
#pragma unroll
    for (int ct = 0; ct < 4; ++ct) {
      uint2v w;
      w[0] = pack2(stl[ct][0], stl[ct][1]);
      w[1] = pack2(stl[ct][2], stl[ct][3]);
      *(uint2v*)&Pt[wid][lm * LDP + ct * 16 + lg * 4] = w;  // Pt[q][key], 8B store
    }
    short8 pf0 = *(const short8*)&Pt[wid][lm * LDP + 0 * 32 + lg * 8];
    short8 pf1 = *(const short8*)&Pt[wid][lm * LDP + 1 * 32 + lg * 8];

    // ---- O += P V  (V^T fragments already in registers)
#pragma unroll
    for (int et = 0; et < 4; ++et) {
      o[et] = MFMA(pf0, vf[et * 2 + 0], o[et]);
      o[et] = MFMA(pf1, vf[et * 2 + 1], o[et]);
    }
  }

  // ---- epilogue: normalize + store fp32 (row q = qrow0 + lg*4 + r, col e = et*16+lm)
  float linv[4];
#pragma unroll
  for (int r = 0; r < 4; ++r) linv[r] = 1.f / __shfl(lsum, lg * 20 + r);
  float* op = O + (((size_t)b * L + qrow0 + lg * 4) * H + h) * E;
#pragma unroll
  for (int r = 0; r < 4; ++r)
#pragma unroll
    for (int et = 0; et < 4; ++et)
      op[(size_t)r * (H * E) + et * 16 + lm] = o[et][r] * linv[r];
}

// ================= fallback (verified v1) for tiny workspaces ==============
constexpr int LDV_F = 72, LDP_F = 72;
__global__ __launch_bounds__(256, 2)
void fattn_v1(const float* __restrict__ Q, const float* __restrict__ K,
              const float* __restrict__ V, float* __restrict__ O) {
  const int qtile = blockIdx.x;
  const int bh = blockIdx.y;
  const int b = bh / H, h = bh % H;
  const int tid = threadIdx.x;
  const int wid = tid >> 6;
  const int lane = tid & 63;
  const int lg = lane >> 4, lm = lane & 15;
  __shared__ __align__(16) short Vs[E * LDV_F];
  __shared__ __align__(16) short Ps[4][16 * LDP_F];
  const int qrow0 = qtile * QBLK + wid * 16;
  short8 qf[2];
  {
    const float* qp = Q + (((size_t)b * L + (qrow0 + lm)) * H + h) * E + lg * 8;
#pragma unroll
    for (int kc = 0; kc < 2; ++kc) {
      f4 a = *(const f4*)(qp + kc * 32);
      f4 c = *(const f4*)(qp + kc * 32 + 4);
      short8 r;
      r[0] = (short)f2bf(a[0] * 0.125f); r[1] = (short)f2bf(a[1] * 0.125f);
      r[2] = (short)f2bf(a[2] * 0.125f); r[3] = (short)f2bf(a[3] * 0.125f);
      r[4] = (short)f2bf(c[0] * 0.125f); r[5] = (short)f2bf(c[1] * 0.125f);
      r[6] = (short)f2bf(c[2] * 0.125f); r[7] = (short)f2bf(c[3] * 0.125f);
      qf[kc] = r;
    }
  }
  f32x4 o[4];
#pragma unroll
  for (int et = 0; et < 4; ++et) o[et] = (f32x4){0.f, 0.f, 0.f, 0.f};
  float mrow[4], lrow[4];
#pragma unroll
  for (int r = 0; r < 4; ++r) { mrow[r] = -1e30f; lrow[r] = 0.f; }
  const float* kbase = K + (((size_t)b * L) * H + h) * E;
  const float* vbase = V + (((size_t)b * L) * H + h) * E;
  const int nkv = qtile + 1;
  for (int kt = 0; kt < nkv; ++kt) {
    __syncthreads();
    {
      const int key = tid >> 2;
      const int eb = (tid & 3) * 16;
      const float* vp = vbase + (size_t)(kt * KVBLK + key) * (H * E) + eb;
#pragma unroll
      for (int i = 0; i < 4; ++i) {
        f4 v = *(const f4*)(vp + i * 4);
        Vs[(eb + i * 4 + 0) * LDV_F + key] = (short)f2bf(v[0]);
        Vs[(eb + i * 4 + 1) * LDV_F + key] = (short)f2bf(v[1]);
        Vs[(eb + i * 4 + 2) * LDV_F + key] = (short)f2bf(v[2]);
        Vs[(eb + i * 4 + 3) * LDV_F + key] = (short)f2bf(v[3]);
      }
    }
    f32x4 s[4];
#pragma unroll
    for (int ct = 0; ct < 4; ++ct) {
      f32x4 acc = (f32x4){0.f, 0.f, 0.f, 0.f};
      const float* kp = kbase + (size_t)(kt * KVBLK + ct * 16 + lm) * (H * E) + lg * 8;
#pragma unroll
      for (int kc = 0; kc < 2; ++kc) {
        f4 a = *(const f4*)(kp + kc * 32);
        f4 c = *(const f4*)(kp + kc * 32 + 4);
        short8 kf;
        kf[0] = (short)f2bf(a[0]); kf[1] = (short)f2bf(a[1]);
        kf[2] = (short)f2bf(a[2]); kf[3] = (short)f2bf(a[3]);
        kf[4] = (short)f2bf(c[0]); kf[5] = (short)f2bf(c[1]);
        kf[6] = (short)f2bf(c[2]); kf[7] = (short)f2bf(c[3]);
        acc = MFMA(qf[kc], kf, acc);
      }
      s[ct] = acc;
    }
    if (kt == nkv - 1) {
#pragma unroll
      for (int ct = 0; ct < 4; ++ct) {
        const int sg = kt * KVBLK + ct * 16 + lm;
#pragma unroll
        for (int r = 0; r < 4; ++r)
          if (sg > qrow0 + lg * 4 + r) s[ct][r] = -1e30f;
      }
    }
#pragma unroll
    for (int r = 0; r < 4; ++r) {
      float tm = fmaxf(fmaxf(s[0][r], s[1][r]), fmaxf(s[2][r], s[3][r]));
      tm = fmaxf(tm, __shfl_xor(tm, 1));
      tm = fmaxf(tm, __shfl_xor(tm, 2));
      tm = fmaxf(tm, __shfl_xor(tm, 4));
      tm = fmaxf(tm, __shfl_xor(tm, 8));
      const float mnew = fmaxf(mrow[r], tm);
      const float sc = __expf(mrow[r] - mnew);
      mrow[r] = mnew;
      float rs = 0.f;
#pragma unroll
      for (int ct = 0; ct < 4; ++ct) {
        const float p = __expf(s[ct][r] - mnew);
        s[ct][r] = p;
        rs += p;
      }
      rs += __shfl_xor(rs, 1);
      rs += __shfl_xor(rs, 2);
      rs += __shfl_xor(rs, 4);
      rs += __shfl_xor(rs, 8);
      lrow[r] = lrow[r] * sc + rs;
#pragma unroll
      for (int et = 0; et < 4; ++et) o[et][r] *= sc;
    }
#pragma unroll
    for (int ct = 0; ct < 4; ++ct)
#pragma unroll
      for (int r = 0; r < 4; ++r)
        Ps[wid][(lg * 4 + r) * LDP_F + ct * 16 + lm] = (short)f2bf(s[ct][r]);
    __syncthreads();
    short8 pf[2];
    pf[0] = *(const short8*)&Ps[wid][lm * LDP_F + 0 * 32 + lg * 8];
    pf[1] = *(const short8*)&Ps[wid][lm * LDP_F + 1 * 32 + lg * 8];
#pragma unroll
    for (int et = 0; et < 4; ++et)
#pragma unroll
      for (int kc = 0; kc < 2; ++kc) {
        short8 vf = *(const short8*)&Vs[(et * 16 + lm) * LDV_F + kc * 32 + lg * 8];
        o[et] = MFMA(pf[kc], vf, o[et]);
      }
  }
  float* op = O + (((size_t)b * L + qrow0) * H + h) * E;
#pragma unroll
  for (int r = 0; r < 4; ++r) {
    const float inv = 1.f / lrow[r];
#pragma unroll
    for (int et = 0; et < 4; ++et)
      op[(size_t)(lg * 4 + r) * (H * E) + et * 16 + lm] = o[et][r] * inv;
  }
}

extern "C" void kernel_launch(void* const* d_in, const int* in_sizes, int n_in,
                              void* d_out, int out_size, void* d_ws, size_t ws_size,
                              hipStream_t stream) {
  const float* Q = (const float*)d_in[0];
  const float* K = (const float*)d_in[1];
  const float* V = (const float*)d_in[2];
  float* Out = (float*)d_out;
  if (ws_size >= WS_NEEDED) {
    unsigned short* Qb = (unsigned short*)d_ws;
    unsigned short* Kb = Qb + NELEM;
    unsigned short* Vt = Kb + NELEM;
    dim3 gc((unsigned)(NELEM / (256 * 8)), 2);
    convert_qk<<<gc, 256, 0, stream>>>(Q, K, Qb, Kb);
    transpose_v<<<B_ * H * (L / KVBLK), 256, 0, stream>>>(V, Vt);
    dim3 grid(B_ * H, L / QBLK);
    fattn2<<<grid, 256, 0, stream>>>(Qb, Kb, Vt, Out);
  } else {
    dim3 grid(L / QBLK, B_ * H);
    fattn_v1<<<grid, 256, 0, stream>>>(Q, K, V, Out);
  }
}